// Round 5
// baseline (24.893 us; speedup 1.0000x reference)
//
#include <hip/hip_runtime.h>
#include <math.h>

#define NUM_CLASSES 80
#define EPSF 1e-7f

constexpr int BS = 32;
constexpr int NT = 20;
constexpr int TOTAL_CELLS = 169 + 676 + 2704;        // 3549
constexpr int TOTAL_POS   = TOTAL_CELLS * 3;         // 10647 anchors per batch
constexpr int THREADS     = 512;
constexpr int CONF_BLKS_PER_B = (TOTAL_POS + THREADS - 1) / THREADS;  // 21
constexpr int CONF_BLKS = CONF_BLKS_PER_B * BS;      // 672
constexpr int POS_BLKS  = (BS * NT) / 8;             // 640 waves / 8 waves per block = 80
constexpr int NBLK = CONF_BLKS + POS_BLKS;           // 752 blocks

__device__ __forceinline__ float sigmoidf_(float x) {
    return 1.0f / (1.0f + expf(-x));
}

// flat anchor index for a target, matching ref semantics exactly
__device__ __forceinline__ int target_flat(float tx, float ty, float tw, float th,
                                           const float* anch) {
    int best = 0; float bestv = -1.0f;
    #pragma unroll
    for (int k = 0; k < 9; ++k) {
        float aw = anch[2 * k], ah = anch[2 * k + 1];
        float inter = fminf(tw, aw) * fminf(th, ah);
        float v = inter / fmaxf(tw * th + aw * ah - inter, EPSF);
        if (v > bestv) { bestv = v; best = k; }  // first max wins (argmax)
    }
    int lvl = best / 3, a = best - lvl * 3;
    int Wl  = (lvl == 0) ? 13 : ((lvl == 1) ? 26 : 52);
    int off = (lvl == 0) ? 0  : ((lvl == 1) ? 507 : 2535);
    float Wf = (float)Wl;
    int X = (int)floorf(tx / 416.0f * Wf);   // exact ref op order
    int Y = (int)floorf(ty / 416.0f * Wf);
    X = min(max(X, 0), Wl - 1);
    Y = min(max(Y, 0), Wl - 1);
    return off + (Y * Wl + X) * 3 + a;
}

__global__ __launch_bounds__(THREADS) void yolo_fused(
    const float* __restrict__ f0, const float* __restrict__ f1,
    const float* __restrict__ f2, const float* __restrict__ tgt,
    const float* __restrict__ anch, float* __restrict__ out)
{
    __shared__ double s_w[8];
    const int bi  = blockIdx.x;
    const int tid = threadIdx.x;
    double lsum = 0.0;

    if (bi < CONF_BLKS) {
        // ---------- objectness BCE + ignore mask: one thread per (anchor, cell) ----------
        __shared__ float s_t[NT][5];
        __shared__ float s_anch[18];
        __shared__ int   s_flat[NT];
        const int b   = bi / CONF_BLKS_PER_B;
        const int sub = bi - b * CONF_BLKS_PER_B;

        // --- issue the conf-channel load EARLY (address independent of staging) ---
        const int idx = sub * THREADS + tid;
        const bool valid = idx < TOTAL_POS;
        int a = 0, cell = 0, lvl = 0, W = 13, cell0 = 0, posoff = 0;
        const float* __restrict__ fb = f0;
        float cl = 0.0f;
        if (valid) {
            a    = idx / TOTAL_CELLS;                    // anchor-major => coalesced
            cell = idx - a * TOTAL_CELLS;
            if (cell < 169)      { lvl = 0; W = 13; cell0 = 0;   posoff = 0;    fb = f0; }
            else if (cell < 845) { lvl = 1; W = 26; cell0 = 169; posoff = 507;  fb = f1; }
            else                 { lvl = 2; W = 52; cell0 = 845; posoff = 2535; fb = f2; }
            cl = fb[((size_t)b * 255 + a * 85 + 4) * (W * W) + (cell - cell0)];
        }

        if (tid < NT * 5) ((float*)s_t)[tid] = tgt[b * NT * 5 + tid];
        if (tid >= 128 && tid < 128 + 18) s_anch[tid - 128] = anch[tid - 128];
        __syncthreads();
        if (tid < NT)
            s_flat[tid] = target_flat(s_t[tid][0], s_t[tid][1], s_t[tid][2], s_t[tid][3], s_anch);
        __syncthreads();

        if (valid) {
            const int HW  = W * W;
            const int rel = cell - cell0;
            const int y   = rel / W;
            const int x   = rel - y * W;
            const int pos = posoff + rel * 3 + a;

            float p = sigmoidf_(cl);
            p = fminf(fmaxf(p, EPSF), 1.0f - EPSF);

            bool assigned = false;
            #pragma unroll
            for (int n = 0; n < NT; ++n) assigned |= (s_flat[n] == pos);

            if (assigned) {
                lsum = -(double)logf(p);                 // positive objectness BCE
            } else {
                const float sxy = 416.0f / (float)W;
                const float acx = ((float)x + 0.5f) * sxy;
                const float acy = ((float)y + 0.5f) * sxy;
                const float aw  = s_anch[(lvl * 3 + a) * 2];
                const float ah  = s_anch[(lvl * 3 + a) * 2 + 1];
                const float anx = acx - aw * 0.5f, axx = acx + aw * 0.5f;
                const float any_ = acy - ah * 0.5f, axy = acy + ah * 0.5f;
                const float aarea = aw * ah;
                float mx = 0.0f;
                #pragma unroll 4
                for (int n = 0; n < NT; ++n) {
                    float tbx = s_t[n][0], tby = s_t[n][1];
                    float tbw = s_t[n][2], tbh = s_t[n][3];
                    float iw = fmaxf(fminf(axx, tbx + tbw * 0.5f) - fmaxf(anx, tbx - tbw * 0.5f), 0.0f);
                    float ih = fmaxf(fminf(axy, tby + tbh * 0.5f) - fmaxf(any_, tby - tbh * 0.5f), 0.0f);
                    float inter = iw * ih;
                    mx = fmaxf(mx, inter / fmaxf(aarea + tbw * tbh - inter, EPSF));
                }
                if (!(mx > 0.5f)) lsum = -(double)logf(1.0f - p);
            }
        }
    } else {
        // ---------- positives (loc + cls): one wave per (batch, target) ----------
        const int wv   = (bi - CONF_BLKS) * 8 + (tid >> 6);
        const int lane = tid & 63;
        const int b = wv / NT;
        const int t = wv - b * NT;

        float an[18];
        #pragma unroll
        for (int k = 0; k < 18; ++k) an[k] = anch[k];    // uniform, cached

        int my_flat = 0x7fffffff;
        if (lane < NT) {
            const float* tp = tgt + ((size_t)b * NT + lane) * 5;
            my_flat = target_flat(tp[0], tp[1], tp[2], tp[3], an);
        }
        const int flat_t = __shfl(my_flat, t);
        bool winner = true;                               // last duplicate wins
        for (int n = t + 1; n < NT; ++n)
            if (__shfl(my_flat, n) == flat_t) winner = false;

        if (winner) {
            int lvl, W, off;
            const float* __restrict__ fb;
            if (flat_t < 507)       { lvl = 0; W = 13; off = 0;    fb = f0; }
            else if (flat_t < 2535) { lvl = 1; W = 26; off = 507;  fb = f1; }
            else                    { lvl = 2; W = 52; off = 2535; fb = f2; }
            const int HW  = W * W;
            const int rel = (flat_t - off) / 3;
            const int a   = flat_t - off - rel * 3;
            const int y   = rel / W;
            const int x   = rel - y * W;
            const float* f = fb + ((size_t)b * 255 + a * 85) * HW + rel;

            const float* tp = tgt + ((size_t)b * NT + t) * 5;
            const float tbx = tp[0], tby = tp[1], tbw = tp[2], tbh = tp[3];
            const int  label = (int)tp[4];

            // ----- class NLL: lanes cover the 80 strided logits in parallel -----
            const int c1 = lane;            // always < 80
            const int c2 = 64 + lane;       // valid for lane < 16
            const float lg1 = f[(size_t)(5 + c1) * HW];
            const float lg2 = (c2 < NUM_CLASSES) ? f[(size_t)(5 + c2) * HW] : -1e30f;
            float m = fmaxf(lg1, lg2);
            #pragma unroll
            for (int s = 32; s > 0; s >>= 1) m = fmaxf(m, __shfl_xor(m, s));
            float ssum = expf(lg1 - m) + ((c2 < NUM_CLASSES) ? expf(lg2 - m) : 0.0f);
            float pick = (c1 == label ? lg1 : 0.0f) + (c2 == label ? lg2 : 0.0f);
            #pragma unroll
            for (int s = 32; s > 0; s >>= 1) {
                ssum += __shfl_xor(ssum, s);
                pick += __shfl_xor(pick, s);
            }
            if (lane == 0) {
                lsum = -(double)(pick - m - logf(ssum));

                // ----- localization (CIoU) -----
                const float sxy = 416.0f / (float)W;
                const float aw = an[(lvl * 3 + a) * 2], ah = an[(lvl * 3 + a) * 2 + 1];
                float px = (sigmoidf_(f[0])              + (float)x) * sxy;
                float py = (sigmoidf_(f[(size_t)HW])     + (float)y) * sxy;
                float pw = expf(f[(size_t)2 * HW]) * aw;
                float ph = expf(f[(size_t)3 * HW]) * ah;

                float b1nx = px - pw * 0.5f, b1xx = px + pw * 0.5f;
                float b1ny = py - ph * 0.5f, b1xy = py + ph * 0.5f;
                float b2nx = tbx - tbw * 0.5f, b2xx = tbx + tbw * 0.5f;
                float b2ny = tby - tbh * 0.5f, b2xy = tby + tbh * 0.5f;
                float iw = fmaxf(fminf(b1xx, b2xx) - fmaxf(b1nx, b2nx), 0.0f);
                float ih = fmaxf(fminf(b1xy, b2xy) - fmaxf(b1ny, b2ny), 0.0f);
                float inter = iw * ih;
                float iou = inter / fmaxf(pw * ph + tbw * tbh - inter, EPSF);
                float cd = (px - tbx) * (px - tbx) + (py - tby) * (py - tby);
                float enx = fminf(b1nx, b2nx), exx = fmaxf(b1xx, b2xx);
                float eny = fminf(b1ny, b2ny), exy = fmaxf(b1xy, b2xy);
                float diag = (exx - enx) * (exx - enx) + (exy - eny) * (exy - eny);
                float ciou = iou - cd / fmaxf(diag, EPSF);
                float dA = atanf(pw / fmaxf(ph, EPSF)) - atanf(tbw / fmaxf(tbh, EPSF));
                float v = (4.0f / (float)(M_PI * M_PI)) * dA * dA;
                float alpha = v / fmaxf(1.0f - iou + v, EPSF);
                float scale = 2.0f - tbw / 416.0f * tbh / 416.0f;
                lsum += (double)((1.0f - (ciou - alpha * v)) * scale);
            }
        }
    }

    // ---------- wave shuffle reduce, cross-wave via LDS, one atomic per block ----------
    #pragma unroll
    for (int s = 32; s > 0; s >>= 1) lsum += __shfl_xor(lsum, s);
    if ((tid & 63) == 0) s_w[tid >> 6] = lsum;
    __syncthreads();
    if (tid == 0) {
        double v = 0.0;
        #pragma unroll
        for (int w = 0; w < 8; ++w) v += s_w[w];
        atomicAdd(out, (float)(v / (double)BS));   // device-scope, no fences needed
    }
}

extern "C" void kernel_launch(void* const* d_in, const int* in_sizes, int n_in,
                              void* d_out, int out_size, void* d_ws, size_t ws_size,
                              hipStream_t stream) {
    const float* f0   = (const float*)d_in[0];
    const float* f1   = (const float*)d_in[1];
    const float* f2   = (const float*)d_in[2];
    const float* tgt  = (const float*)d_in[3];
    const float* anch = (const float*)d_in[4];

    hipMemsetAsync(d_out, 0, sizeof(float), stream);   // accumulator starts at 0 each call
    yolo_fused<<<NBLK, THREADS, 0, stream>>>(f0, f1, f2, tgt, anch, (float*)d_out);
}

// Round 6
// 18.874 us; speedup vs baseline: 1.3189x; 1.3189x over previous
//
#include <hip/hip_runtime.h>
#include <math.h>

#define NUM_CLASSES 80
#define EPSF 1e-7f

constexpr int BS = 32;
constexpr int NT = 20;
constexpr int TOTAL_CELLS = 169 + 676 + 2704;        // 3549
constexpr int TOTAL_POS   = TOTAL_CELLS * 3;         // 10647 anchors per batch
constexpr int THREADS     = 512;
constexpr int CONF_BLKS_PER_B = (TOTAL_POS + THREADS - 1) / THREADS;  // 21
constexpr int CONF_BLKS = CONF_BLKS_PER_B * BS;      // 672
constexpr int POS_BLKS  = (BS * NT) / 8;             // 640 waves / 8 waves per block = 80
constexpr int NBLK = CONF_BLKS + POS_BLKS;           // 752 partials

__device__ __forceinline__ float sigmoidf_(float x) {
    return 1.0f / (1.0f + expf(-x));
}

// flat anchor index for a target, matching ref semantics exactly
__device__ __forceinline__ int target_flat(float tx, float ty, float tw, float th,
                                           const float* anch) {
    int best = 0; float bestv = -1.0f;
    #pragma unroll
    for (int k = 0; k < 9; ++k) {
        float aw = anch[2 * k], ah = anch[2 * k + 1];
        float inter = fminf(tw, aw) * fminf(th, ah);
        float v = inter / fmaxf(tw * th + aw * ah - inter, EPSF);
        if (v > bestv) { bestv = v; best = k; }  // first max wins (argmax)
    }
    int lvl = best / 3, a = best - lvl * 3;
    int Wl  = (lvl == 0) ? 13 : ((lvl == 1) ? 26 : 52);
    int off = (lvl == 0) ? 0  : ((lvl == 1) ? 507 : 2535);
    float Wf = (float)Wl;
    int X = (int)floorf(tx / 416.0f * Wf);   // exact ref op order
    int Y = (int)floorf(ty / 416.0f * Wf);
    X = min(max(X, 0), Wl - 1);
    Y = min(max(Y, 0), Wl - 1);
    return off + (Y * Wl + X) * 3 + a;
}

__global__ __launch_bounds__(THREADS) void yolo_fused(
    const float* __restrict__ f0, const float* __restrict__ f1,
    const float* __restrict__ f2, const float* __restrict__ tgt,
    const float* __restrict__ anch, double* __restrict__ part)
{
    __shared__ double s_w[8];
    const int bi  = blockIdx.x;
    const int tid = threadIdx.x;
    double lsum = 0.0;

    if (bi < CONF_BLKS) {
        // ---------- objectness BCE + ignore mask: one thread per (anchor, cell) ----------
        __shared__ float s_t[NT][5];
        __shared__ float s_anch[18];
        __shared__ int   s_flat[NT];
        const int b   = bi / CONF_BLKS_PER_B;
        const int sub = bi - b * CONF_BLKS_PER_B;

        if (tid < NT * 5) ((float*)s_t)[tid] = tgt[b * NT * 5 + tid];
        if (tid >= 128 && tid < 128 + 18) s_anch[tid - 128] = anch[tid - 128];
        __syncthreads();
        if (tid < NT)
            s_flat[tid] = target_flat(s_t[tid][0], s_t[tid][1], s_t[tid][2], s_t[tid][3], s_anch);
        __syncthreads();

        const int idx = sub * THREADS + tid;
        if (idx < TOTAL_POS) {
            const int a    = idx / TOTAL_CELLS;          // anchor-major => coalesced
            const int cell = idx - a * TOTAL_CELLS;
            int lvl, W, cell0, posoff;
            const float* __restrict__ fb;
            if (cell < 169)      { lvl = 0; W = 13; cell0 = 0;   posoff = 0;    fb = f0; }
            else if (cell < 845) { lvl = 1; W = 26; cell0 = 169; posoff = 507;  fb = f1; }
            else                 { lvl = 2; W = 52; cell0 = 845; posoff = 2535; fb = f2; }
            const int HW  = W * W;
            const int rel = cell - cell0;
            const int y   = rel / W;
            const int x   = rel - y * W;
            const int pos = posoff + rel * 3 + a;

            const float cl = fb[((size_t)b * 255 + a * 85 + 4) * HW + rel];
            float p = sigmoidf_(cl);
            p = fminf(fmaxf(p, EPSF), 1.0f - EPSF);

            bool assigned = false;
            #pragma unroll
            for (int n = 0; n < NT; ++n) assigned |= (s_flat[n] == pos);

            if (assigned) {
                lsum = -(double)logf(p);                 // positive objectness BCE
            } else {
                const float sxy = 416.0f / (float)W;
                const float acx = ((float)x + 0.5f) * sxy;
                const float acy = ((float)y + 0.5f) * sxy;
                const float aw  = s_anch[(lvl * 3 + a) * 2];
                const float ah  = s_anch[(lvl * 3 + a) * 2 + 1];
                const float anx = acx - aw * 0.5f, axx = acx + aw * 0.5f;
                const float any_ = acy - ah * 0.5f, axy = acy + ah * 0.5f;
                const float aarea = aw * ah;
                float mx = 0.0f;
                #pragma unroll 4
                for (int n = 0; n < NT; ++n) {
                    float tbx = s_t[n][0], tby = s_t[n][1];
                    float tbw = s_t[n][2], tbh = s_t[n][3];
                    float iw = fmaxf(fminf(axx, tbx + tbw * 0.5f) - fmaxf(anx, tbx - tbw * 0.5f), 0.0f);
                    float ih = fmaxf(fminf(axy, tby + tbh * 0.5f) - fmaxf(any_, tby - tbh * 0.5f), 0.0f);
                    float inter = iw * ih;
                    mx = fmaxf(mx, inter / fmaxf(aarea + tbw * tbh - inter, EPSF));
                }
                if (!(mx > 0.5f)) lsum = -(double)logf(1.0f - p);
            }
        }
    } else {
        // ---------- positives (loc + cls): one wave per (batch, target) ----------
        const int wv   = (bi - CONF_BLKS) * 8 + (tid >> 6);
        const int lane = tid & 63;
        const int b = wv / NT;
        const int t = wv - b * NT;

        float an[18];
        #pragma unroll
        for (int k = 0; k < 18; ++k) an[k] = anch[k];    // uniform, cached

        int my_flat = 0x7fffffff;
        if (lane < NT) {
            const float* tp = tgt + ((size_t)b * NT + lane) * 5;
            my_flat = target_flat(tp[0], tp[1], tp[2], tp[3], an);
        }
        const int flat_t = __shfl(my_flat, t);
        bool winner = true;                               // last duplicate wins
        for (int n = t + 1; n < NT; ++n)
            if (__shfl(my_flat, n) == flat_t) winner = false;

        if (winner) {
            int lvl, W, off;
            const float* __restrict__ fb;
            if (flat_t < 507)       { lvl = 0; W = 13; off = 0;    fb = f0; }
            else if (flat_t < 2535) { lvl = 1; W = 26; off = 507;  fb = f1; }
            else                    { lvl = 2; W = 52; off = 2535; fb = f2; }
            const int HW  = W * W;
            const int rel = (flat_t - off) / 3;
            const int a   = flat_t - off - rel * 3;
            const int y   = rel / W;
            const int x   = rel - y * W;
            const float* f = fb + ((size_t)b * 255 + a * 85) * HW + rel;

            const float* tp = tgt + ((size_t)b * NT + t) * 5;
            const float tbx = tp[0], tby = tp[1], tbw = tp[2], tbh = tp[3];
            const int  label = (int)tp[4];

            // ----- class NLL: lanes cover the 80 strided logits in parallel -----
            const int c1 = lane;            // always < 80
            const int c2 = 64 + lane;       // valid for lane < 16
            const float lg1 = f[(size_t)(5 + c1) * HW];
            const float lg2 = (c2 < NUM_CLASSES) ? f[(size_t)(5 + c2) * HW] : -1e30f;
            float m = fmaxf(lg1, lg2);
            #pragma unroll
            for (int s = 32; s > 0; s >>= 1) m = fmaxf(m, __shfl_xor(m, s));
            float ssum = expf(lg1 - m) + ((c2 < NUM_CLASSES) ? expf(lg2 - m) : 0.0f);
            float pick = (c1 == label ? lg1 : 0.0f) + (c2 == label ? lg2 : 0.0f);
            #pragma unroll
            for (int s = 32; s > 0; s >>= 1) {
                ssum += __shfl_xor(ssum, s);
                pick += __shfl_xor(pick, s);
            }
            if (lane == 0) {
                lsum = -(double)(pick - m - logf(ssum));

                // ----- localization (CIoU) -----
                const float sxy = 416.0f / (float)W;
                const float aw = an[(lvl * 3 + a) * 2], ah = an[(lvl * 3 + a) * 2 + 1];
                float px = (sigmoidf_(f[0])              + (float)x) * sxy;
                float py = (sigmoidf_(f[(size_t)HW])     + (float)y) * sxy;
                float pw = expf(f[(size_t)2 * HW]) * aw;
                float ph = expf(f[(size_t)3 * HW]) * ah;

                float b1nx = px - pw * 0.5f, b1xx = px + pw * 0.5f;
                float b1ny = py - ph * 0.5f, b1xy = py + ph * 0.5f;
                float b2nx = tbx - tbw * 0.5f, b2xx = tbx + tbw * 0.5f;
                float b2ny = tby - tbh * 0.5f, b2xy = tby + tbh * 0.5f;
                float iw = fmaxf(fminf(b1xx, b2xx) - fmaxf(b1nx, b2nx), 0.0f);
                float ih = fmaxf(fminf(b1xy, b2xy) - fmaxf(b1ny, b2ny), 0.0f);
                float inter = iw * ih;
                float iou = inter / fmaxf(pw * ph + tbw * tbh - inter, EPSF);
                float cd = (px - tbx) * (px - tbx) + (py - tby) * (py - tby);
                float enx = fminf(b1nx, b2nx), exx = fmaxf(b1xx, b2xx);
                float eny = fminf(b1ny, b2ny), exy = fmaxf(b1xy, b2xy);
                float diag = (exx - enx) * (exx - enx) + (exy - eny) * (exy - eny);
                float ciou = iou - cd / fmaxf(diag, EPSF);
                float dA = atanf(pw / fmaxf(ph, EPSF)) - atanf(tbw / fmaxf(tbh, EPSF));
                float v = (4.0f / (float)(M_PI * M_PI)) * dA * dA;
                float alpha = v / fmaxf(1.0f - iou + v, EPSF);
                float scale = 2.0f - tbw / 416.0f * tbh / 416.0f;
                lsum += (double)((1.0f - (ciou - alpha * v)) * scale);
            }
        }
    }

    // ---------- wave shuffle reduce, then cross-wave via LDS (single barrier) ----------
    #pragma unroll
    for (int s = 32; s > 0; s >>= 1) lsum += __shfl_xor(lsum, s);
    if ((tid & 63) == 0) s_w[tid >> 6] = lsum;
    __syncthreads();
    if (tid == 0) {
        double v = 0.0;
        #pragma unroll
        for (int w = 0; w < 8; ++w) v += s_w[w];
        part[bi] = v;
    }
}

__global__ __launch_bounds__(256) void yolo_finish(const double* __restrict__ part,
                                                   float* __restrict__ out)
{
    __shared__ double s_w[4];
    const int tid = threadIdx.x;
    double v = 0.0;
    for (int i = tid; i < NBLK; i += 256) v += part[i];
    #pragma unroll
    for (int s = 32; s > 0; s >>= 1) v += __shfl_xor(v, s);
    if ((tid & 63) == 0) s_w[tid >> 6] = v;
    __syncthreads();
    if (tid == 0) out[0] = (float)((s_w[0] + s_w[1] + s_w[2] + s_w[3]) / (double)BS);
}

extern "C" void kernel_launch(void* const* d_in, const int* in_sizes, int n_in,
                              void* d_out, int out_size, void* d_ws, size_t ws_size,
                              hipStream_t stream) {
    const float* f0   = (const float*)d_in[0];
    const float* f1   = (const float*)d_in[1];
    const float* f2   = (const float*)d_in[2];
    const float* tgt  = (const float*)d_in[3];
    const float* anch = (const float*)d_in[4];
    double* part = (double*)d_ws;                 // NBLK doubles = 6 KB

    yolo_fused<<<NBLK, THREADS, 0, stream>>>(f0, f1, f2, tgt, anch, part);
    yolo_finish<<<1, 256, 0, stream>>>(part, (float*)d_out);
}

// Round 7
// 18.721 us; speedup vs baseline: 1.3297x; 1.0082x over previous
//
#include <hip/hip_runtime.h>
#include <math.h>

#define NUM_CLASSES 80
#define EPSF 1e-7f

constexpr int BS = 32;
constexpr int NT = 20;
constexpr int TOTAL_CELLS = 169 + 676 + 2704;        // 3549
constexpr int TOTAL_POS   = TOTAL_CELLS * 3;         // 10647 anchors per batch
constexpr int THREADS     = 512;
constexpr int CONF_BLKS_PER_B = (TOTAL_POS + THREADS - 1) / THREADS;  // 21
constexpr int CONF_BLKS = CONF_BLKS_PER_B * BS;      // 672
constexpr int POS_BLKS  = (BS * NT) / 8;             // 640 waves / 8 waves per block = 80
constexpr int NBLK = CONF_BLKS + POS_BLKS;           // 752 partials

__device__ __forceinline__ float sigmoidf_(float x) {
    return 1.0f / (1.0f + expf(-x));
}

// flat anchor index for a target, matching ref semantics exactly
__device__ __forceinline__ int target_flat(float tx, float ty, float tw, float th,
                                           const float* anch) {
    int best = 0; float bestv = -1.0f;
    #pragma unroll
    for (int k = 0; k < 9; ++k) {
        float aw = anch[2 * k], ah = anch[2 * k + 1];
        float inter = fminf(tw, aw) * fminf(th, ah);
        float v = inter / fmaxf(tw * th + aw * ah - inter, EPSF);
        if (v > bestv) { bestv = v; best = k; }  // first max wins (argmax)
    }
    int lvl = best / 3, a = best - lvl * 3;
    int Wl  = (lvl == 0) ? 13 : ((lvl == 1) ? 26 : 52);
    int off = (lvl == 0) ? 0  : ((lvl == 1) ? 507 : 2535);
    float Wf = (float)Wl;
    int X = (int)floorf(tx / 416.0f * Wf);   // exact ref op order
    int Y = (int)floorf(ty / 416.0f * Wf);
    X = min(max(X, 0), Wl - 1);
    Y = min(max(Y, 0), Wl - 1);
    return off + (Y * Wl + X) * 3 + a;
}

__global__ __launch_bounds__(THREADS) void yolo_fused(
    const float* __restrict__ f0, const float* __restrict__ f1,
    const float* __restrict__ f2, const float* __restrict__ tgt,
    const float* __restrict__ anch, double* __restrict__ part)
{
    __shared__ double s_w[8];
    const int bi  = blockIdx.x;
    const int tid = threadIdx.x;
    double lsum = 0.0;

    if (bi < CONF_BLKS) {
        // ---------- objectness BCE + ignore mask: one thread per (anchor, cell) ----------
        __shared__ float s_t[NT][5];
        __shared__ int   s_flat[NT];
        const int b   = bi / CONF_BLKS_PER_B;
        const int sub = bi - b * CONF_BLKS_PER_B;

        // --- early conf-channel load: address independent of staging, miss hides
        //     under the target-staging chain below ---
        const int idx = sub * THREADS + tid;
        const bool valid = idx < TOTAL_POS;
        int a = 0, cell = 0, lvl = 0, W = 13, cell0 = 0, posoff = 0;
        float cl = 0.0f;
        if (valid) {
            a    = idx / TOTAL_CELLS;                    // anchor-major => coalesced
            cell = idx - a * TOTAL_CELLS;
            const float* __restrict__ fb;
            if (cell < 169)      { lvl = 0; W = 13; cell0 = 0;   posoff = 0;    fb = f0; }
            else if (cell < 845) { lvl = 1; W = 26; cell0 = 169; posoff = 507;  fb = f1; }
            else                 { lvl = 2; W = 52; cell0 = 845; posoff = 2535; fb = f2; }
            cl = fb[((size_t)b * 255 + a * 85 + 4) * (W * W) + (cell - cell0)];
        }

        // --- single-barrier staging: lanes 0..19 own one target each ---
        if (tid < NT) {
            const float* tp = tgt + ((size_t)b * NT + tid) * 5;
            const float t0 = tp[0], t1 = tp[1], t2 = tp[2], t3 = tp[3], t4 = tp[4];
            s_t[tid][0] = t0; s_t[tid][1] = t1; s_t[tid][2] = t2;
            s_t[tid][3] = t3; s_t[tid][4] = t4;
            s_flat[tid] = target_flat(t0, t1, t2, t3, anch);  // anch: uniform s_loads
        }
        __syncthreads();

        if (valid) {
            const int HW  = W * W;
            const int rel = cell - cell0;
            const int y   = rel / W;
            const int x   = rel - y * W;
            const int pos = posoff + rel * 3 + a;

            float p = sigmoidf_(cl);
            p = fminf(fmaxf(p, EPSF), 1.0f - EPSF);

            bool assigned = false;
            #pragma unroll
            for (int n = 0; n < NT; ++n) assigned |= (s_flat[n] == pos);

            if (assigned) {
                lsum = -(double)logf(p);                 // positive objectness BCE
            } else {
                const float sxy = 416.0f / (float)W;
                const float acx = ((float)x + 0.5f) * sxy;
                const float acy = ((float)y + 0.5f) * sxy;
                const float aw  = anch[(lvl * 3 + a) * 2];      // L1-hot
                const float ah  = anch[(lvl * 3 + a) * 2 + 1];
                const float anx = acx - aw * 0.5f, axx = acx + aw * 0.5f;
                const float any_ = acy - ah * 0.5f, axy = acy + ah * 0.5f;
                const float aarea = aw * ah;
                float mx = 0.0f;
                #pragma unroll 4
                for (int n = 0; n < NT; ++n) {
                    float tbx = s_t[n][0], tby = s_t[n][1];
                    float tbw = s_t[n][2], tbh = s_t[n][3];
                    float iw = fmaxf(fminf(axx, tbx + tbw * 0.5f) - fmaxf(anx, tbx - tbw * 0.5f), 0.0f);
                    float ih = fmaxf(fminf(axy, tby + tbh * 0.5f) - fmaxf(any_, tby - tbh * 0.5f), 0.0f);
                    float inter = iw * ih;
                    mx = fmaxf(mx, inter / fmaxf(aarea + tbw * tbh - inter, EPSF));
                }
                if (!(mx > 0.5f)) lsum = -(double)logf(1.0f - p);
            }
        }
    } else {
        // ---------- positives (loc + cls): one wave per (batch, target) ----------
        const int wv   = (bi - CONF_BLKS) * 8 + (tid >> 6);
        const int lane = tid & 63;
        const int b = wv / NT;
        const int t = wv - b * NT;

        float an[18];
        #pragma unroll
        for (int k = 0; k < 18; ++k) an[k] = anch[k];    // uniform, cached

        int my_flat = 0x7fffffff;
        if (lane < NT) {
            const float* tp = tgt + ((size_t)b * NT + lane) * 5;
            my_flat = target_flat(tp[0], tp[1], tp[2], tp[3], an);
        }
        const int flat_t = __shfl(my_flat, t);
        bool winner = true;                               // last duplicate wins
        for (int n = t + 1; n < NT; ++n)
            if (__shfl(my_flat, n) == flat_t) winner = false;

        if (winner) {
            int lvl, W, off;
            const float* __restrict__ fb;
            if (flat_t < 507)       { lvl = 0; W = 13; off = 0;    fb = f0; }
            else if (flat_t < 2535) { lvl = 1; W = 26; off = 507;  fb = f1; }
            else                    { lvl = 2; W = 52; off = 2535; fb = f2; }
            const int HW  = W * W;
            const int rel = (flat_t - off) / 3;
            const int a   = flat_t - off - rel * 3;
            const int y   = rel / W;
            const int x   = rel - y * W;
            const float* f = fb + ((size_t)b * 255 + a * 85) * HW + rel;

            const float* tp = tgt + ((size_t)b * NT + t) * 5;
            const float tbx = tp[0], tby = tp[1], tbw = tp[2], tbh = tp[3];
            const int  label = (int)tp[4];

            // ----- class NLL: lanes cover the 80 strided logits in parallel -----
            const int c1 = lane;            // always < 80
            const int c2 = 64 + lane;       // valid for lane < 16
            const float lg1 = f[(size_t)(5 + c1) * HW];
            const float lg2 = (c2 < NUM_CLASSES) ? f[(size_t)(5 + c2) * HW] : -1e30f;
            float m = fmaxf(lg1, lg2);
            #pragma unroll
            for (int s = 32; s > 0; s >>= 1) m = fmaxf(m, __shfl_xor(m, s));
            float ssum = expf(lg1 - m) + ((c2 < NUM_CLASSES) ? expf(lg2 - m) : 0.0f);
            float pick = (c1 == label ? lg1 : 0.0f) + (c2 == label ? lg2 : 0.0f);
            #pragma unroll
            for (int s = 32; s > 0; s >>= 1) {
                ssum += __shfl_xor(ssum, s);
                pick += __shfl_xor(pick, s);
            }
            if (lane == 0) {
                lsum = -(double)(pick - m - logf(ssum));

                // ----- localization (CIoU) -----
                const float sxy = 416.0f / (float)W;
                const float aw = an[(lvl * 3 + a) * 2], ah = an[(lvl * 3 + a) * 2 + 1];
                float px = (sigmoidf_(f[0])              + (float)x) * sxy;
                float py = (sigmoidf_(f[(size_t)HW])     + (float)y) * sxy;
                float pw = expf(f[(size_t)2 * HW]) * aw;
                float ph = expf(f[(size_t)3 * HW]) * ah;

                float b1nx = px - pw * 0.5f, b1xx = px + pw * 0.5f;
                float b1ny = py - ph * 0.5f, b1xy = py + ph * 0.5f;
                float b2nx = tbx - tbw * 0.5f, b2xx = tbx + tbw * 0.5f;
                float b2ny = tby - tbh * 0.5f, b2xy = tby + tbh * 0.5f;
                float iw = fmaxf(fminf(b1xx, b2xx) - fmaxf(b1nx, b2nx), 0.0f);
                float ih = fmaxf(fminf(b1xy, b2xy) - fmaxf(b1ny, b2ny), 0.0f);
                float inter = iw * ih;
                float iou = inter / fmaxf(pw * ph + tbw * tbh - inter, EPSF);
                float cd = (px - tbx) * (px - tbx) + (py - tby) * (py - tby);
                float enx = fminf(b1nx, b2nx), exx = fmaxf(b1xx, b2xx);
                float eny = fminf(b1ny, b2ny), exy = fmaxf(b1xy, b2xy);
                float diag = (exx - enx) * (exx - enx) + (exy - eny) * (exy - eny);
                float ciou = iou - cd / fmaxf(diag, EPSF);
                float dA = atanf(pw / fmaxf(ph, EPSF)) - atanf(tbw / fmaxf(tbh, EPSF));
                float v = (4.0f / (float)(M_PI * M_PI)) * dA * dA;
                float alpha = v / fmaxf(1.0f - iou + v, EPSF);
                float scale = 2.0f - tbw / 416.0f * tbh / 416.0f;
                lsum += (double)((1.0f - (ciou - alpha * v)) * scale);
            }
        }
    }

    // ---------- wave shuffle reduce, then cross-wave via LDS (single barrier) ----------
    #pragma unroll
    for (int s = 32; s > 0; s >>= 1) lsum += __shfl_xor(lsum, s);
    if ((tid & 63) == 0) s_w[tid >> 6] = lsum;
    __syncthreads();
    if (tid == 0) {
        double v = 0.0;
        #pragma unroll
        for (int w = 0; w < 8; ++w) v += s_w[w];
        part[bi] = v;
    }
}

__global__ __launch_bounds__(256) void yolo_finish(const double* __restrict__ part,
                                                   float* __restrict__ out)
{
    __shared__ double s_w[4];
    const int tid = threadIdx.x;
    double v = 0.0;
    for (int i = tid; i < NBLK; i += 256) v += part[i];
    #pragma unroll
    for (int s = 32; s > 0; s >>= 1) v += __shfl_xor(v, s);
    if ((tid & 63) == 0) s_w[tid >> 6] = v;
    __syncthreads();
    if (tid == 0) out[0] = (float)((s_w[0] + s_w[1] + s_w[2] + s_w[3]) / (double)BS);
}

extern "C" void kernel_launch(void* const* d_in, const int* in_sizes, int n_in,
                              void* d_out, int out_size, void* d_ws, size_t ws_size,
                              hipStream_t stream) {
    const float* f0   = (const float*)d_in[0];
    const float* f1   = (const float*)d_in[1];
    const float* f2   = (const float*)d_in[2];
    const float* tgt  = (const float*)d_in[3];
    const float* anch = (const float*)d_in[4];
    double* part = (double*)d_ws;                 // NBLK doubles = 6 KB

    yolo_fused<<<NBLK, THREADS, 0, stream>>>(f0, f1, f2, tgt, anch, part);
    yolo_finish<<<1, 256, 0, stream>>>(part, (float*)d_out);
}